// Round 2
// baseline (811.267 us; speedup 1.0000x reference)
//
#include <hip/hip_runtime.h>

#define NEGV (-1e9f)

constexpr int BN   = 64;
constexpr int S1   = 257;
constexpr int LEN  = 32;
constexpr int CH   = S1 * S1;          // 66049
constexpr int ROWS = LEN + 1;          // 33
constexpr int ABSZ = BN * ROWS * S1;   // 542784

// d_out layout (floats), reference return order: M, ll, a, b, ls, p, t
constexpr int OFF_M  = 0;
constexpr int OFF_LL = 64;
constexpr int OFF_A  = OFF_LL + ABSZ;
constexpr int OFF_B  = OFF_A + ABSZ;
constexpr int OFF_LS = OFF_B + ABSZ;
constexpr int OFF_P  = OFF_LS + 64;
constexpr int OFF_T  = OFF_P + ABSZ;

// workspace layout (floats)
constexpr int WS_CS = 0;               // 64*3*257 = 49344
constexpr int WS_M  = BN * 3 * S1;     // +64
constexpr int WS_QT = WS_M + 64;       // 3*66049

// ---------------------------------------------------------------- prep:
__global__ __launch_bounds__(256) void k_prep(const float* __restrict__ logits,
                                              const int* __restrict__ ls,
                                              float* __restrict__ ws,
                                              float* __restrict__ out) {
  __shared__ float sC[3][256];
  const int b = blockIdx.x;
  const int tid = threadIdx.x;
  {
    float l0 = logits[(b*3+0)*256 + tid];
    float l1 = logits[(b*3+1)*256 + tid];
    float l2 = logits[(b*3+2)*256 + tid];
    float mm = fmaxf(l0, fmaxf(l1, l2));
    float lse = mm + __logf(__expf(l0-mm) + __expf(l1-mm) + __expf(l2-mm));
    sC[0][tid] = l0 - lse;
    sC[1][tid] = l1 - lse;
    sC[2][tid] = l2 - lse;
  }
  __syncthreads();
  const int w = tid >> 6, lane = tid & 63;
  if (w < 3) {
    float* cs = ws + WS_CS + b*771 + w*257;
    if (lane == 0) cs[0] = 0.f;
    float carry = 0.f;
    for (int t = 0; t < 4; ++t) {
      float v = sC[w][t*64 + lane];
      #pragma unroll
      for (int off = 1; off < 64; off <<= 1) {
        float o = __shfl_up(v, off);
        if (lane >= off) v += o;
      }
      cs[t*64 + lane + 1] = carry + v;
      carry += __shfl(v, 63);
    }
  }
  if (tid == 0) out[OFF_LS + b] = (float)ls[b];
}

// ---------------------------------------------------------------- Q transpose
__global__ __launch_bounds__(256) void k_qt(const float* __restrict__ Q,
                                            float* __restrict__ QT) {
  const int cj = blockIdx.x;           // c*257 + j
  const int c = cj / 257, j = cj - c*257;
  const float* Qc = Q + c*CH;
  float* QTc = QT + c*CH;
  for (int i = threadIdx.x; i < S1; i += 256)
    QTc[j*257 + i] = Qc[i*257 + j];
}

// ---------------------------------------------------------------- recursion:
// blocks 0..63 -> alpha(b), 64..127 -> beta(b). 1024 thr: 4 lanes per output row.
// Two-pass register-cached logsumexp: pass1 = load x[64] + max (4 indep chains),
// pass2 = sum exp(x-m) (4 indep accumulators). All exps independent.
__global__ __launch_bounds__(1024) void k_rec(const float* __restrict__ Q,
                                              const float* __restrict__ QT,
                                              const int* __restrict__ pattern,
                                              const int* __restrict__ ls,
                                              float* __restrict__ ws,
                                              float* __restrict__ out) {
  __shared__ float csS[771];
  __shared__ float u4[264];    // alpha: u=la-cs ; beta: w=lb+cs (4-way interleaved; slot 260 = idx 256)
  __shared__ float aux4[264];  // beta: lb copy (for row i=256)
  __shared__ float vS[257];    // la / lb
  __shared__ int patS[32];
  const int tid = threadIdx.x;
  const bool isBeta = (blockIdx.x >= BN);
  const int b = isBeta ? (blockIdx.x - BN) : blockIdx.x;
  for (int i = tid; i < 771; i += 1024) csS[i] = ws[WS_CS + b*771 + i];
  if (tid < 32) patS[tid] = pattern[tid];
  const int lsb = ls[b];
  const int jj = tid >> 2, q = tid & 3;
  float* outab = out + (isBeta ? OFF_B : OFF_A) + b * (ROWS * S1);

  if (!isBeta) {
    for (int i2 = tid; i2 < S1; i2 += 1024) {
      float v = (i2 == 0) ? 0.f : NEGV;
      vS[i2] = v;
      outab[i2] = v;                         // a row 0
    }
    __syncthreads();
    for (int step = 0; step < LEN; ++step) {
      const int c = patS[step];
      const float la256 = vS[256];
      if (tid < 256) u4[((tid & 63) << 2) | (tid >> 6)] = vS[tid] - csS[c*257 + tid];
      __syncthreads();
      const float* Qc = Q + c*CH;
      for (int row = jj; row < S1; row += 256) {
        const int lim = (row < 256) ? row : 256;   // valid i in [0,lim)
        const int lo = q << 6;
        int n = lim - lo; n = (n < 0) ? 0 : ((n > 64) ? 64 : n);
        const float* qp = Qc + lo*257 + row;
        float x[64];
        #pragma unroll
        for (int kk = 0; kk < 64; ++kk) {
          float xv = qp[kk*257] + u4[(kk << 2) | q];
          x[kk] = (kk < n) ? xv : -1e30f;
        }
        float m0=-1e30f, m1=-1e30f, m2=-1e30f, m3=-1e30f;
        #pragma unroll
        for (int kk = 0; kk < 64; kk += 4) {
          m0 = fmaxf(m0, x[kk]);   m1 = fmaxf(m1, x[kk+1]);
          m2 = fmaxf(m2, x[kk+2]); m3 = fmaxf(m3, x[kk+3]);
        }
        float m = fmaxf(fmaxf(m0, m1), fmaxf(m2, m3));
        float s0=0.f, s1=0.f, s2=0.f, s3=0.f;
        #pragma unroll
        for (int kk = 0; kk < 64; kk += 4) {
          s0 += __expf(x[kk]   - m); s1 += __expf(x[kk+1] - m);
          s2 += __expf(x[kk+2] - m); s3 += __expf(x[kk+3] - m);
        }
        float s = (s0 + s1) + (s2 + s3);
        #pragma unroll
        for (int off = 1; off < 4; off <<= 1) {
          float om = __shfl_xor(m, off);
          float os = __shfl_xor(s, off);
          float nm = fmaxf(m, om);
          s = s * __expf(m - nm) + os * __expf(om - nm);
          m = nm;
        }
        float A = csS[c*257 + row] + m + __logf(s);    // ~-1e30 iff row empty
        float Bv = Qc[256*257 + row] + la256;          // i=256 path, always finite
        float h = fmaxf(A, Bv), l = fminf(A, Bv);
        float r = h + __logf(1.f + __expf(l - h));
        if (q == 0) {
          vS[row] = r;
          outab[(step + 1) * S1 + row] = r;
        }
      }
      __syncthreads();
    }
    if (tid == 0) {
      float Mv = vS[lsb];
      ws[WS_M + b] = Mv;
      out[OFF_M + b] = Mv;
    }
  } else {
    for (int i2 = tid; i2 < S1; i2 += 1024) {
      float v = (i2 == lsb) ? 0.f : NEGV;
      vS[i2] = v;
      outab[LEN * S1 + i2] = v;                // b row 32
    }
    __syncthreads();
    for (int step = LEN - 1; step >= 0; --step) {
      const int c = patS[step];
      if (tid < S1) {
        float lb = vS[tid];
        int slot = (tid < 256) ? (((tid & 63) << 2) | (tid >> 6)) : 260;
        u4[slot] = lb + csS[c*257 + tid];
        aux4[slot] = lb;
      }
      __syncthreads();
      const float* QTc = QT + c*CH;
      const float* Qc = Q + c*CH;
      for (int row = jj; row < S1; row += 256) {
        const int qlo = q << 6;
        float x[64];
        if (row < 256) {
          const float* qp = QTc + qlo*257 + row;
          #pragma unroll
          for (int kk = 0; kk < 64; ++kk) {
            int j2 = qlo + kk;                 // <= 255
            float xv = qp[kk*257] + u4[(kk << 2) | q];
            x[kk] = (j2 > row) ? xv : -1e30f;
          }
        } else {                               // row i = 256: P==0 for all j
          const float* qp = Qc + 256*257 + qlo;
          #pragma unroll
          for (int kk = 0; kk < 64; ++kk) {
            x[kk] = qp[kk] + aux4[(kk << 2) | q];
          }
        }
        // j = 256 epilogue folded into lane q==3 (zeroed in combine if spurious)
        float xe;
        if (row < 256) xe = (q == 3) ? (QTc[256*257 + row] + u4[260]) : -1e30f;
        else           xe = (q == 3) ? (Qc[256*257 + 256] + aux4[260]) : -1e30f;

        float m0=xe, m1=-1e30f, m2=-1e30f, m3=-1e30f;
        #pragma unroll
        for (int kk = 0; kk < 64; kk += 4) {
          m0 = fmaxf(m0, x[kk]);   m1 = fmaxf(m1, x[kk+1]);
          m2 = fmaxf(m2, x[kk+2]); m3 = fmaxf(m3, x[kk+3]);
        }
        float m = fmaxf(fmaxf(m0, m1), fmaxf(m2, m3));
        float s0, s1=0.f, s2=0.f, s3=0.f;
        s0 = __expf(xe - m);
        #pragma unroll
        for (int kk = 0; kk < 64; kk += 4) {
          s0 += __expf(x[kk]   - m); s1 += __expf(x[kk+1] - m);
          s2 += __expf(x[kk+2] - m); s3 += __expf(x[kk+3] - m);
        }
        float s = (s0 + s1) + (s2 + s3);
        #pragma unroll
        for (int off = 1; off < 4; off <<= 1) {
          float om = __shfl_xor(m, off);
          float os = __shfl_xor(s, off);
          float nm = fmaxf(m, om);
          s = s * __expf(m - nm) + os * __expf(om - nm);
          m = nm;
        }
        float r = m + __logf(s);
        if (row < 256) r -= csS[c*257 + row];
        if (q == 0) {
          vS[row] = r;
          outab[step * S1 + row] = r;
        }
      }
      __syncthreads();
    }
  }
}

// ---------------------------------------------------------------- ll & p
__global__ __launch_bounds__(256) void k_llp(const float* __restrict__ ws,
                                             float* __restrict__ out) {
  int idx = blockIdx.x * 256 + threadIdx.x;
  if (idx >= ABSZ) return;
  int b = idx / (ROWS * S1);
  float a = out[OFF_A + idx];
  float bb = out[OFF_B + idx];
  float ll = a + bb;
  __builtin_nontemporal_store(ll, out + OFF_LL + idx);
  __builtin_nontemporal_store(ll - ws[WS_M + b], out + OFF_P + idx);
}

// ---------------------------------------------------------------- t (541 MB)
__global__ __launch_bounds__(256) void k_t(const float* __restrict__ Q,
                                           const int* __restrict__ pattern,
                                           const float* __restrict__ ws,
                                           float* __restrict__ out) {
  __shared__ float r1[257], r2[257], c1[257], c2[257];
  const int bk = blockIdx.x;
  const int b = bk >> 5, k = bk & 31;
  const int c = pattern[k];
  const float Mb = ws[WS_M + b];
  const int tid = threadIdx.x;
  const float* cs = ws + WS_CS + b*771 + c*257;
  const float* ar = out + OFF_A + (b*ROWS + k) * S1;
  const float* br = out + OFF_B + (b*ROWS + k + 1) * S1;
  for (int i = tid; i < S1; i += 256) {
    float av = ar[i], cv = cs[i], bv = br[i];
    r1[i] = av - cv - Mb;                       // used when j > i  (P = cs[j]-cs[i])
    r2[i] = av - Mb + ((i == 256) ? 0.f : NEGV);// P = 0 (row 256) or NEG
    c1[i] = bv + cv;
    c2[i] = bv;
  }
  __syncthreads();
  const float* Qc = Q + c*CH;
  float* tb = out + OFF_T + (size_t)bk * CH;
  int i = 0, j = tid;                           // idx = i*257 + j, diagonal march
  for (int idx = tid; idx < CH; idx += 256) {
    float qv = Qc[idx];
    float v = (j > i) ? (r1[i] + c1[j]) : (r2[i] + c2[j]);
    __builtin_nontemporal_store(qv + v, tb + idx);
    bool wr = (j == 0);
    i += wr ? 0 : 1;
    j = wr ? 256 : (j - 1);
  }
}

extern "C" void kernel_launch(void* const* d_in, const int* in_sizes, int n_in,
                              void* d_out, int out_size, void* d_ws, size_t ws_size,
                              hipStream_t stream) {
  const float* logits = (const float*)d_in[0];
  const float* Q      = (const float*)d_in[1];
  const int* pattern  = (const int*)d_in[2];
  const int* ls       = (const int*)d_in[3];
  float* out = (float*)d_out;
  float* ws  = (float*)d_ws;

  k_prep<<<BN, 256, 0, stream>>>(logits, ls, ws, out);
  k_qt<<<3*S1, 256, 0, stream>>>(Q, ws + WS_QT);
  k_rec<<<2*BN, 1024, 0, stream>>>(Q, ws + WS_QT, pattern, ls, ws, out);
  k_llp<<<(ABSZ + 255)/256, 256, 0, stream>>>(ws, out);
  k_t<<<BN*LEN, 256, 0, stream>>>(Q, pattern, ws, out);
}

// Round 4
// 489.234 us; speedup vs baseline: 1.6582x; 1.6582x over previous
//
#include <hip/hip_runtime.h>

#define NEGV (-1e9f)

constexpr int BN   = 64;
constexpr int S1   = 257;
constexpr int LEN  = 32;
constexpr int CH   = S1 * S1;          // 66049
constexpr int ROWS = LEN + 1;          // 33
constexpr int ABSZ = BN * ROWS * S1;   // 542784
constexpr int EQP  = 258;              // padded row stride
constexpr int EQC  = S1 * EQP;         // 66306 per channel

// d_out layout (floats), reference return order: M, ll, a, b, ls, p, t
constexpr int OFF_M  = 0;
constexpr int OFF_LL = 64;
constexpr int OFF_A  = OFF_LL + ABSZ;
constexpr int OFF_B  = OFF_A + ABSZ;
constexpr int OFF_LS = OFF_B + ABSZ;
constexpr int OFF_P  = OFF_LS + 64;
constexpr int OFF_T  = OFF_P + ABSZ;   // 2,171,264 (even -> 8B aligned)

// workspace layout (floats)
constexpr int WS_CS = 0;               // fp32 cs, 64*771
constexpr int WS_M  = 64 * 771;        // +64

// scratch carved out of the (not yet written) t-region of d_out (floats)
constexpr int TS_CSD = OFF_T;                  // fp64 cs: 64*771 doubles = 98688 floats
constexpr int TS_EQ  = OFF_T + 2 * 64 * 771;   // 3*EQC floats
constexpr int TS_EQT = TS_EQ + 3 * EQC;        // 3*EQC floats

// ---------------------------------------------------------------- fp64 helpers
__device__ __forceinline__ double dexp(double x) {      // |x| < ~420
  double t = x * 1.4426950408889634;                    // log2(e)
  double n = floor(t);
  float  f = (float)(t - n);                            // [0,1)
  double r = (double)exp2f(f);                          // [1,2)
  long long bb = __double_as_longlong(r);
  bb += ((long long)n) << 52;                           // scale by 2^n
  return __longlong_as_double(bb);
}
__device__ __forceinline__ double dlog(double x) {      // x > 0, normal
  long long bb = __double_as_longlong(x);
  int e = (int)((bb >> 52) & 0x7ff) - 1023;
  bb = (bb & 0xFFFFFFFFFFFFFLL) | 0x3FF0000000000000LL;
  float m = (float)__longlong_as_double(bb);
  return (double)__logf(m) + (double)e * 0.6931471805599453;
}
__device__ __forceinline__ float dlogf(double x) {      // log(x), NEGV for 0/subnormal
  if (!(x > 1e-300)) return NEGV;
  long long bb = __double_as_longlong(x);
  int e = (int)((bb >> 52) & 0x7ff) - 1023;
  bb = (bb & 0xFFFFFFFFFFFFFLL) | 0x3FF0000000000000LL;
  float m = (float)__longlong_as_double(bb);
  return __logf(m) + (float)e * 0.69314718055994531f;
}

// ---------------------------------------------------------------- prep:
// log_softmax + prefix-sum (fp64 master, fp32 copy for k_t). ls -> out.
__global__ __launch_bounds__(256) void k_prep(const float* __restrict__ logits,
                                              const int* __restrict__ ls,
                                              float* __restrict__ ws,
                                              float* __restrict__ out) {
  __shared__ float sC[3][256];
  const int b = blockIdx.x;
  const int tid = threadIdx.x;
  {
    float l0 = logits[(b*3+0)*256 + tid];
    float l1 = logits[(b*3+1)*256 + tid];
    float l2 = logits[(b*3+2)*256 + tid];
    float mm = fmaxf(l0, fmaxf(l1, l2));
    float lse = mm + __logf(__expf(l0-mm) + __expf(l1-mm) + __expf(l2-mm));
    sC[0][tid] = l0 - lse;
    sC[1][tid] = l1 - lse;
    sC[2][tid] = l2 - lse;
  }
  __syncthreads();
  const int w = tid >> 6, lane = tid & 63;
  double* csD = (double*)(out + TS_CSD);
  if (w < 3) {
    float*  cs32 = ws + WS_CS + b*771 + w*257;
    double* csd  = csD + b*771 + w*257;
    if (lane == 0) { cs32[0] = 0.f; csd[0] = 0.0; }
    double carry = 0.0;
    for (int t = 0; t < 4; ++t) {
      double v = (double)sC[w][t*64 + lane];
      #pragma unroll
      for (int off = 1; off < 64; off <<= 1) {
        double o = __shfl_up(v, off);
        if (lane >= off) v += o;
      }
      double r = carry + v;
      cs32[t*64 + lane + 1] = (float)r;
      csd [t*64 + lane + 1] = r;
      carry += __shfl(v, 63);
    }
  }
  if (tid == 0) out[OFF_LS + b] = (float)ls[b];
}

// ---------------------------------------------------------------- EQ = exp(Q), EQT = transpose
__global__ __launch_bounds__(256) void k_eq(const float* __restrict__ Q,
                                            float* __restrict__ out) {
  const int blk = blockIdx.x;            // c*257 + i
  const int c = blk / 257, i = blk - c*257;
  float* EQ  = out + TS_EQ;
  float* EQT = out + TS_EQT;
  const float* Qr = Q + c*CH + i*S1;
  for (int j = threadIdx.x; j < S1; j += 256) {
    float e = __expf(Qr[j]);
    EQ [c*EQC + i*EQP + j] = e;          // coalesced
    EQT[c*EQC + j*EQP + i] = e;          // scattered (small, once)
  }
}

// ---------------------------------------------------------------- recursion (fp64 linear matvec)
// blocks 0..63 -> alpha(b), 64..127 -> beta(b). 1024 thr = 4 i(j)-chunks x 256 cols.
__global__ __launch_bounds__(1024) void k_rec(const float* __restrict__ outRO,
                                              const int* __restrict__ pattern,
                                              const int* __restrict__ ls,
                                              float* __restrict__ ws,
                                              float* __restrict__ out) {
  __shared__ double ecsP[3][257], ecsM[3][257]; // e^{cs}, e^{-cs} per channel
  __shared__ double AD[258];                    // carried normalized state (A or B)
  __shared__ double wD[258];                    // alpha: A*e^{-cs} ; beta: B*e^{+cs}
  __shared__ double ArD[258];                   // raw next-state
  __shared__ double part[4][264];               // chunk partials
  __shared__ double sSDinv, sLn, sMv;
  __shared__ int patS[LEN];
  const int tid = threadIdx.x;
  const bool isBeta = (blockIdx.x >= BN);
  const int b = isBeta ? (blockIdx.x - BN) : blockIdx.x;
  const float* EQ  = outRO + TS_EQ;
  const float* EQT = outRO + TS_EQT;
  const double* csD = (const double*)(outRO + TS_CSD) + b*771;

  if (tid < LEN) patS[tid] = pattern[tid];
  const int lsb = ls[b];
  for (int idx = tid; idx < 771; idx += 1024) {
    int c = idx / 257, j = idx - c*257;
    double x = csD[idx];
    ecsP[c][j] = dexp(x);
    ecsM[c][j] = dexp(-x);
  }
  if (tid == 0) sLn = 0.0;
  // chunk q never writes its own "freed" slot: zero it once.
  if (tid < 4) part[tid][isBeta ? tid*64 + 63 : tid*64] = 0.0;

  float* outab = out + (isBeta ? OFF_B : OFF_A) + b * (ROWS * S1);
  const int q = tid >> 8, tl = tid & 255;

  if (tid < S1) {
    double a0 = isBeta ? (tid == lsb ? 1.0 : 0.0) : (tid == 0 ? 1.0 : 0.0);
    AD[tid] = a0;
    outab[(isBeta ? LEN : 0) * S1 + tid] = (a0 > 0.0) ? 0.0f : NEGV;
  }
  __syncthreads();

  if (!isBeta) {
    for (int step = 0; step < LEN; ++step) {
      const int c = patS[step];
      if (tid < S1) wD[tid] = AD[tid] * ecsM[c][tid];
      __syncthreads();
      const float* EQc = EQ + c*EQC;
      {
        const int ej = (tl == (q << 6)) ? 256 : tl;   // freed diag thread -> col 256
        int n = ej - (q << 6); n = n < 0 ? 0 : (n > 64 ? 64 : n);
        double acc = 0.0;
        const float*  p  = EQc + (q << 6) * EQP + ej;
        const double* wp = &wD[q << 6];
        #pragma unroll 4
        for (int k = 0; k < n; ++k) acc += wp[k] * (double)p[k * EQP];
        part[q][ej] = acc;
      }
      __syncthreads();
      if (tid < S1) {
        const int j = tid;
        double sum = part[0][j] + part[1][j] + part[2][j] + part[3][j];
        double Ar = ecsP[c][j] * sum + AD[256] * (double)EQc[256*EQP + j];
        ArD[j] = Ar;
        float lo = dlogf(Ar);
        outab[(step + 1) * S1 + j] = (float)((double)lo + sLn);
        if (step == LEN - 1 && j == lsb) sMv = (double)lo + sLn;
      }
      __syncthreads();
      if (tid < 64) {
        double s = ArD[tid] + ArD[tid+64] + ArD[tid+128] + ArD[tid+192];
        if (tid == 0) s += ArD[256];
        #pragma unroll
        for (int off = 32; off; off >>= 1) s += __shfl_xor(s, off);
        if (tid == 0) { sSDinv = 1.0 / s; sLn += dlog(s); }
      }
      __syncthreads();
      if (tid < S1) AD[tid] = ArD[tid] * sSDinv;
      __syncthreads();
    }
    if (tid == 0) {
      out[OFF_M + b] = (float)sMv;
      ws[WS_M + b]   = (float)sMv;
    }
  } else {
    for (int step = LEN - 1; step >= 0; --step) {
      const int c = patS[step];
      if (tid < S1) wD[tid] = AD[tid] * ecsP[c][tid];      // v = B * e^{cs}
      __syncthreads();
      const float* EQc  = EQ  + c*EQC;
      const float* EQTc = EQT + c*EQC;
      {
        const int ei = (tl == (q << 6) + 63) ? 256 : tl;   // freed diag thread -> row 256
        double acc = 0.0;
        if (ei < 256) {
          int k0 = ei + 1 - (q << 6); k0 = k0 < 0 ? 0 : k0;
          const float*  p  = EQTc + (q << 6) * EQP + ei;
          const double* vp = &wD[q << 6];
          #pragma unroll 4
          for (int k = k0; k < 64; ++k) acc += vp[k] * (double)p[k * EQP];
        } else {
          const float*  p  = EQc + 256*EQP + (q << 6);
          const double* ap = &AD[q << 6];
          #pragma unroll 4
          for (int k = 0; k < 64; ++k) acc += ap[k] * (double)p[k];
        }
        part[q][ei] = acc;
      }
      __syncthreads();
      if (tid < S1) {
        const int i = tid;
        double sum = part[0][i] + part[1][i] + part[2][i] + part[3][i];
        double Br;
        if (i < 256) Br = ecsM[c][i] * (sum + (double)EQc[i*EQP + 256] * wD[256]);
        else         Br = sum + (double)EQc[256*EQP + 256] * AD[256];
        ArD[i] = Br;
        outab[step * S1 + i] = (float)((double)dlogf(Br) + sLn);
      }
      __syncthreads();
      if (tid < 64) {
        double s = ArD[tid] + ArD[tid+64] + ArD[tid+128] + ArD[tid+192];
        if (tid == 0) s += ArD[256];
        #pragma unroll
        for (int off = 32; off; off >>= 1) s += __shfl_xor(s, off);
        if (tid == 0) { sSDinv = 1.0 / s; sLn += dlog(s); }
      }
      __syncthreads();
      if (tid < S1) AD[tid] = ArD[tid] * sSDinv;
      __syncthreads();
    }
  }
}

// ---------------------------------------------------------------- ll & p
__global__ __launch_bounds__(256) void k_llp(const float* __restrict__ ws,
                                             float* __restrict__ out) {
  int idx = blockIdx.x * 256 + threadIdx.x;
  if (idx >= ABSZ) return;
  int b = idx / (ROWS * S1);
  float a = out[OFF_A + idx];
  float bb = out[OFF_B + idx];
  float ll = a + bb;
  __builtin_nontemporal_store(ll, out + OFF_LL + idx);
  __builtin_nontemporal_store(ll - ws[WS_M + b], out + OFF_P + idx);
}

// ---------------------------------------------------------------- t (541 MB)
__global__ __launch_bounds__(256) void k_t(const float* __restrict__ Q,
                                           const int* __restrict__ pattern,
                                           const float* __restrict__ ws,
                                           float* __restrict__ out) {
  __shared__ float r1[257], r2[257], c1[257], c2[257];
  const int bk = blockIdx.x;
  const int b = bk >> 5, k = bk & 31;
  const int c = pattern[k];
  const float Mb = ws[WS_M + b];
  const int tid = threadIdx.x;
  const float* cs = ws + WS_CS + b*771 + c*257;
  const float* ar = out + OFF_A + (b*ROWS + k) * S1;
  const float* br = out + OFF_B + (b*ROWS + k + 1) * S1;
  for (int i = tid; i < S1; i += 256) {
    float av = ar[i], cv = cs[i], bv = br[i];
    r1[i] = av - cv - Mb;                        // j > i : P = cs[j]-cs[i]
    r2[i] = av - Mb + ((i == 256) ? 0.f : NEGV); // row 256: P=0, else NEG
    c1[i] = bv + cv;
    c2[i] = bv;
  }
  __syncthreads();
  const float* Qc = Q + c*CH;
  float* tb = out + OFF_T + (size_t)bk * CH;
  int i = 0, j = tid;                            // idx = i*257 + j diagonal march
  for (int idx = tid; idx < CH; idx += 256) {
    float qv = Qc[idx];
    float v = (j > i) ? (r1[i] + c1[j]) : (r2[i] + c2[j]);
    __builtin_nontemporal_store(qv + v, tb + idx);
    bool wr = (j == 0);
    i += wr ? 0 : 1;
    j = wr ? 256 : (j - 1);
  }
}

extern "C" void kernel_launch(void* const* d_in, const int* in_sizes, int n_in,
                              void* d_out, int out_size, void* d_ws, size_t ws_size,
                              hipStream_t stream) {
  const float* logits = (const float*)d_in[0];
  const float* Q      = (const float*)d_in[1];
  const int* pattern  = (const int*)d_in[2];
  const int* ls       = (const int*)d_in[3];
  float* out = (float*)d_out;
  float* ws  = (float*)d_ws;

  k_prep<<<BN, 256, 0, stream>>>(logits, ls, ws, out);
  k_eq<<<3*S1, 256, 0, stream>>>(Q, out);
  k_rec<<<2*BN, 1024, 0, stream>>>(out, pattern, ls, ws, out);
  k_llp<<<(ABSZ + 255)/256, 256, 0, stream>>>(ws, out);
  k_t<<<BN*LEN, 256, 0, stream>>>(Q, pattern, ws, out);
}

// Round 5
// 440.475 us; speedup vs baseline: 1.8418x; 1.1107x over previous
//
#include <hip/hip_runtime.h>

#define NEGV (-1e9f)

constexpr int BN   = 64;
constexpr int S1   = 257;
constexpr int LEN  = 32;
constexpr int CH   = S1 * S1;          // 66049
constexpr int ROWS = LEN + 1;          // 33
constexpr int ABSZ = BN * ROWS * S1;   // 542784
constexpr int EQP  = 260;              // padded row stride (16B-aligned rows)
constexpr int EQC  = S1 * EQP;         // 66820 per channel (mult of 4)

// d_out layout (floats), reference return order: M, ll, a, b, ls, p, t
constexpr int OFF_M  = 0;
constexpr int OFF_LL = 64;
constexpr int OFF_A  = OFF_LL + ABSZ;  // 542848
constexpr int OFF_B  = OFF_A + ABSZ;   // 1085632
constexpr int OFF_LS = OFF_B + ABSZ;   // 1628416
constexpr int OFF_P  = OFF_LS + 64;    // 1628480
constexpr int OFF_T  = OFF_P + ABSZ;   // 2171264 (mult of 4 -> 16B aligned)

// workspace layout (floats)
constexpr int WS_CS = 0;               // fp32 cs, 64*771
constexpr int WS_M  = 64 * 771;        // +64

// scratch carved out of the (not yet written) t-region of d_out (floats)
constexpr int TS_CSD = OFF_T;                  // fp64 cs: 64*771 doubles = 98688 floats
constexpr int TS_EQ  = OFF_T + 2 * 64 * 771;   // 3*EQC floats (mult-of-4 offset)
constexpr int TS_EQT = TS_EQ + 3 * EQC;        // 3*EQC floats (mult-of-4 offset)

// ---------------------------------------------------------------- fp64 helpers
__device__ __forceinline__ double dexp(double x) {      // |x| < ~600
  double t = x * 1.4426950408889634;                    // log2(e)
  double n = floor(t);
  float  f = (float)(t - n);                            // [0,1)
  double r = (double)exp2f(f);                          // [1,2)
  long long bb = __double_as_longlong(r);
  bb += ((long long)n) << 52;                           // scale by 2^n
  return __longlong_as_double(bb);
}
__device__ __forceinline__ float dlogf(double x) {      // log(x), NEGV for <=0/tiny
  if (!(x > 1e-300)) return NEGV;
  long long bb = __double_as_longlong(x);
  int e = (int)((bb >> 52) & 0x7ff) - 1023;
  bb = (bb & 0xFFFFFFFFFFFFFLL) | 0x3FF0000000000000LL;
  float m = (float)__longlong_as_double(bb);
  return __logf(m) + (float)e * 0.69314718055994531f;
}

// ---------------------------------------------------------------- pre:
// blocks 0..770: EQ = exp(Q) (+transpose). blocks 771..834: per-batch log_softmax
// + prefix-sum (fp64 master in t-scratch, fp32 copy in ws). ls -> out.
__global__ __launch_bounds__(256) void k_pre(const float* __restrict__ logits,
                                             const float* __restrict__ Q,
                                             const int* __restrict__ ls,
                                             float* __restrict__ ws,
                                             float* __restrict__ out) {
  const int blk = blockIdx.x;
  const int tid = threadIdx.x;
  if (blk < 3 * S1) {
    const int c = blk / S1, i = blk - c * S1;
    float* EQ  = out + TS_EQ;
    float* EQT = out + TS_EQT;
    const float* Qr = Q + c * CH + i * S1;
    for (int j = tid; j < S1; j += 256) {
      float e = __expf(Qr[j]);
      EQ [c * EQC + i * EQP + j] = e;     // coalesced
      EQT[c * EQC + j * EQP + i] = e;     // scatter (once, small)
    }
    return;
  }
  const int b = blk - 3 * S1;
  __shared__ float sC[3][256];
  {
    float l0 = logits[(b*3+0)*256 + tid];
    float l1 = logits[(b*3+1)*256 + tid];
    float l2 = logits[(b*3+2)*256 + tid];
    float mm = fmaxf(l0, fmaxf(l1, l2));
    float lse = mm + __logf(__expf(l0-mm) + __expf(l1-mm) + __expf(l2-mm));
    sC[0][tid] = l0 - lse;
    sC[1][tid] = l1 - lse;
    sC[2][tid] = l2 - lse;
  }
  __syncthreads();
  const int w = tid >> 6, lane = tid & 63;
  double* csD = (double*)(out + TS_CSD);
  if (w < 3) {
    float*  cs32 = ws + WS_CS + b*771 + w*257;
    double* csd  = csD + b*771 + w*257;
    if (lane == 0) { cs32[0] = 0.f; csd[0] = 0.0; }
    double carry = 0.0;
    for (int t = 0; t < 4; ++t) {
      double v = (double)sC[w][t*64 + lane];
      #pragma unroll
      for (int off = 1; off < 64; off <<= 1) {
        double o = __shfl_up(v, off);
        if (lane >= off) v += o;
      }
      double r = carry + v;
      cs32[t*64 + lane + 1] = (float)r;
      csd [t*64 + lane + 1] = r;
      carry += __shfl(v, 63);
    }
  }
  if (tid == 0) out[OFF_LS + b] = (float)ls[b];
}

// ---------------------------------------------------------------- recursion
// Raw (unnormalized) fp64 linear recursion; range fits fp64 (see analysis).
// blocks 0..63 alpha(b), 64..127 beta(b). 1024 thr = 16 waves; wave w owns
// rows k in [16w,16w+16); lane owns 4 output cols. 2 barriers per step.
__global__ __launch_bounds__(1024) void k_rec(const float* __restrict__ outRO,
                                              const int* __restrict__ pattern,
                                              const int* __restrict__ ls,
                                              float* __restrict__ ws,
                                              float* __restrict__ out) {
  __shared__ double ecsP[3][257], ecsM[3][257];
  __shared__ double wDp[2][258];    // weight vec (parity-buffered); [*][256] = raw state[256] (alpha) / wD[256] (beta)
  __shared__ double AD[258];        // beta only: raw B state
  __shared__ double part[16][260];  // per-wave partials; [w][256] = col/row-256 partial
  __shared__ int patS[LEN];
  const int tid = threadIdx.x;
  const bool isBeta = (blockIdx.x >= BN);
  const int b = isBeta ? (blockIdx.x - BN) : blockIdx.x;
  const float* EQ  = outRO + TS_EQ;
  const float* EQT = outRO + TS_EQT;
  const double* csD = (const double*)(outRO + TS_CSD) + b * 771;

  if (tid < LEN) patS[tid] = pattern[tid];
  const int lsb = ls[b];
  for (int idx = tid; idx < 771; idx += 1024) {
    int c = idx / 257, j = idx - c * 257;
    double x = csD[idx];
    ecsP[c][j] = dexp(x);
    ecsM[c][j] = dexp(-x);
  }
  float* outab = out + (isBeta ? OFF_B : OFF_A) + b * (ROWS * S1);
  const int w = tid >> 6, l = tid & 63;
  const int k0 = w << 4, col0 = l << 2;

  if (tid < S1) {
    if (!isBeta) {
      wDp[0][tid] = (tid == 0) ? 1.0 : 0.0;      // A0 * e^{-cs}: e^{-cs[0]}=1
      outab[tid] = (tid == 0) ? 0.f : NEGV;
    } else {
      AD[tid] = (tid == lsb) ? 1.0 : 0.0;
      wDp[0][tid] = (tid == lsb) ? ecsP[patS[LEN-1]][tid] : 0.0;
      outab[LEN * S1 + tid] = (tid == lsb) ? 0.f : NEGV;
    }
  }
  __syncthreads();

  int cur = 0;
  if (!isBeta) {
    for (int step = 0; step < LEN; ++step, cur ^= 1) {
      const int c = patS[step];
      const float* EQc  = EQ  + c * EQC;
      const float* EQTc = EQT + c * EQC;
      {  // matvec partials: cols col0..col0+3, rows k0..k0+15, valid i<j
        const double* wc = wDp[cur];
        double a0 = 0, a1 = 0, a2 = 0, a3 = 0;
        const float* bp = EQc + k0 * EQP + col0;
        #pragma unroll
        for (int kk = 0; kk < 16; ++kk) {
          const int k = k0 + kk;
          float4 e = *(const float4*)(bp + kk * EQP);
          double wv = wc[k];
          a0 += wv * (double)((k < col0    ) ? e.x : 0.f);
          a1 += wv * (double)((k < col0 + 1) ? e.y : 0.f);
          a2 += wv * (double)((k < col0 + 2) ? e.z : 0.f);
          a3 += wv * (double)((k < col0 + 3) ? e.w : 0.f);
        }
        part[w][col0] = a0; part[w][col0+1] = a1;
        part[w][col0+2] = a2; part[w][col0+3] = a3;
        double c2 = 0;                         // col-256 partial
        if (l < 16) c2 = wc[k0 + l] * (double)EQTc[256 * EQP + k0 + l];
        c2 += __shfl_xor(c2, 1); c2 += __shfl_xor(c2, 2);
        c2 += __shfl_xor(c2, 4); c2 += __shfl_xor(c2, 8);
        if (l == 0) part[w][256] = c2;
      }
      __syncthreads();
      if (tid < S1) {
        const int j = tid;
        double sum = 0;
        #pragma unroll
        for (int w2 = 0; w2 < 16; ++w2) sum += part[w2][j];
        double Ar = ecsP[c][j] * sum + wDp[cur][256] * (double)EQc[256 * EQP + j];
        float lo = dlogf(Ar);
        outab[(step + 1) * S1 + j] = lo;
        if (step == LEN - 1) {
          if (j == lsb) { out[OFF_M + b] = lo; ws[WS_M + b] = lo; }
        } else {
          const int cn = patS[step + 1];
          wDp[cur ^ 1][j] = (j < 256) ? Ar * ecsM[cn][j] : Ar;  // slot 256 = raw A[256]
        }
      }
      __syncthreads();
    }
  } else {
    for (int ss = 0; ss < LEN; ++ss, cur ^= 1) {
      const int step = LEN - 1 - ss;
      const int c = patS[step];
      const float* EQc  = EQ  + c * EQC;
      const float* EQTc = EQT + c * EQC;
      {  // partials for output rows i=col0.., k walks j in [k0,k0+16), valid j>i
        const double* wc = wDp[cur];
        double a0 = 0, a1 = 0, a2 = 0, a3 = 0;
        const float* bp = EQTc + k0 * EQP + col0;
        #pragma unroll
        for (int kk = 0; kk < 16; ++kk) {
          const int k = k0 + kk;
          float4 e = *(const float4*)(bp + kk * EQP);
          double wv = wc[k];
          a0 += wv * (double)((k > col0    ) ? e.x : 0.f);
          a1 += wv * (double)((k > col0 + 1) ? e.y : 0.f);
          a2 += wv * (double)((k > col0 + 2) ? e.z : 0.f);
          a3 += wv * (double)((k > col0 + 3) ? e.w : 0.f);
        }
        part[w][col0] = a0; part[w][col0+1] = a1;
        part[w][col0+2] = a2; part[w][col0+3] = a3;
        double r2 = 0;                         // row-256 output partial
        if (l < 16) r2 = AD[k0 + l] * (double)EQc[256 * EQP + k0 + l];
        r2 += __shfl_xor(r2, 1); r2 += __shfl_xor(r2, 2);
        r2 += __shfl_xor(r2, 4); r2 += __shfl_xor(r2, 8);
        if (l == 0) part[w][256] = r2;
      }
      __syncthreads();
      if (tid < S1) {
        const int i = tid;
        double sum = 0;
        #pragma unroll
        for (int w2 = 0; w2 < 16; ++w2) sum += part[w2][i];
        double Ar;
        if (i < 256)
          Ar = ecsM[c][i] * (sum + (double)EQTc[256 * EQP + i] * wDp[cur][256]);
        else
          Ar = sum + (double)EQc[256 * EQP + 256] * AD[256];
        outab[step * S1 + i] = dlogf(Ar);
        AD[i] = Ar;
        if (ss < LEN - 1) {
          const int cn = patS[step - 1];
          wDp[cur ^ 1][i] = Ar * ecsP[cn][i];   // incl. i=256: wD256=B256*e^{cs256}
        }
      }
      __syncthreads();
    }
  }
}

// ---------------------------------------------------------------- ll & p
__global__ __launch_bounds__(256) void k_llp(const float* __restrict__ ws,
                                             float* __restrict__ out) {
  int idx = blockIdx.x * 256 + threadIdx.x;
  if (idx >= ABSZ) return;
  int b = idx / (ROWS * S1);
  float a = out[OFF_A + idx];
  float bb = out[OFF_B + idx];
  float ll = a + bb;
  __builtin_nontemporal_store(ll, out + OFF_LL + idx);
  __builtin_nontemporal_store(ll - ws[WS_M + b], out + OFF_P + idx);
}

// ---------------------------------------------------------------- t (541 MB)
__global__ __launch_bounds__(256) void k_t(const float* __restrict__ Q,
                                           const int* __restrict__ pattern,
                                           const float* __restrict__ ws,
                                           float* __restrict__ out) {
  __shared__ float r1[257], r2[257], c1[257], c2[257];
  const int bk = blockIdx.x;
  const int b = bk >> 5, k = bk & 31;
  const int c = pattern[k];
  const float Mb = ws[WS_M + b];
  const int tid = threadIdx.x;
  const float* cs = ws + WS_CS + b*771 + c*257;
  const float* ar = out + OFF_A + (b*ROWS + k) * S1;
  const float* br = out + OFF_B + (b*ROWS + k + 1) * S1;
  for (int i = tid; i < S1; i += 256) {
    float av = ar[i], cv = cs[i], bv = br[i];
    r1[i] = av - cv - Mb;                        // j > i : P = cs[j]-cs[i]
    r2[i] = av - Mb + ((i == 256) ? 0.f : NEGV); // row 256: P=0, else NEG
    c1[i] = bv + cv;
    c2[i] = bv;
  }
  __syncthreads();
  const float* Qc = Q + c*CH;
  float* tb = out + OFF_T + (size_t)bk * CH;
  int i = 0, j = tid;                            // idx = i*257 + j diagonal march
  for (int idx = tid; idx < CH; idx += 256) {
    float qv = Qc[idx];
    float v = (j > i) ? (r1[i] + c1[j]) : (r2[i] + c2[j]);
    __builtin_nontemporal_store(qv + v, tb + idx);
    bool wr = (j == 0);
    i += wr ? 0 : 1;
    j = wr ? 256 : (j - 1);
  }
}

extern "C" void kernel_launch(void* const* d_in, const int* in_sizes, int n_in,
                              void* d_out, int out_size, void* d_ws, size_t ws_size,
                              hipStream_t stream) {
  const float* logits = (const float*)d_in[0];
  const float* Q      = (const float*)d_in[1];
  const int* pattern  = (const int*)d_in[2];
  const int* ls       = (const int*)d_in[3];
  float* out = (float*)d_out;
  float* ws  = (float*)d_ws;

  k_pre<<<3*S1 + BN, 256, 0, stream>>>(logits, Q, ls, ws, out);
  k_rec<<<2*BN, 1024, 0, stream>>>(out, pattern, ls, ws, out);
  k_llp<<<(ABSZ + 255)/256, 256, 0, stream>>>(ws, out);
  k_t<<<BN*LEN, 256, 0, stream>>>(Q, pattern, ws, out);
}

// Round 6
// 394.054 us; speedup vs baseline: 2.0588x; 1.1178x over previous
//
#include <hip/hip_runtime.h>

#define NEGV (-1e9f)

constexpr int BN   = 64;
constexpr int S1   = 257;
constexpr int LEN  = 32;
constexpr int CH   = S1 * S1;          // 66049
constexpr int ROWS = LEN + 1;          // 33
constexpr int ABSZ = BN * ROWS * S1;   // 542784
constexpr int EQP  = 260;              // padded row stride (16B-aligned rows)
constexpr int EQC  = S1 * EQP;         // 66820 per channel

// d_out layout (floats), reference return order: M, ll, a, b, ls, p, t
constexpr int OFF_M  = 0;
constexpr int OFF_LL = 64;
constexpr int OFF_A  = OFF_LL + ABSZ;
constexpr int OFF_B  = OFF_A + ABSZ;
constexpr int OFF_LS = OFF_B + ABSZ;
constexpr int OFF_P  = OFF_LS + 64;
constexpr int OFF_T  = OFF_P + ABSZ;   // 2171264 (mult of 4 -> 16B aligned)

// workspace layout (floats)
constexpr int WS_CS  = 0;              // fp32 cs, 64*771
constexpr int WS_M   = 64 * 771;       // +64
constexpr int WS_SCR = WS_M + 64;      // 49408 (16B aligned)

// scratch-relative offsets (floats); scratch = ws+WS_SCR if it fits, else out+OFF_T
constexpr int SC_CSD = 0;                      // fp64 cs: 64*771 doubles
constexpr int SC_EQ  = 2 * 64 * 771;           // 98688
constexpr int SC_EQT = SC_EQ + 3 * EQC;        // +200460
constexpr int SC_END = SC_EQT + 3 * EQC;       // 499608 floats ~ 2 MB

// ---------------------------------------------------------------- fp64 helpers
__device__ __forceinline__ double dexp(double x) {      // |x| < ~600
  double t = x * 1.4426950408889634;                    // log2(e)
  double n = floor(t);
  float  f = (float)(t - n);                            // [0,1)
  double r = (double)exp2f(f);                          // [1,2)
  long long bb = __double_as_longlong(r);
  bb += ((long long)n) << 52;                           // scale by 2^n
  return __longlong_as_double(bb);
}
__device__ __forceinline__ float dlogf(double x) {      // log(x), NEGV for <=0/tiny
  if (!(x > 1e-300)) return NEGV;
  long long bb = __double_as_longlong(x);
  int e = (int)((bb >> 52) & 0x7ff) - 1023;
  bb = (bb & 0xFFFFFFFFFFFFFLL) | 0x3FF0000000000000LL;
  float m = (float)__longlong_as_double(bb);
  return __logf(m) + (float)e * 0.69314718055994531f;
}

// ---------------------------------------------------------------- pre:
// blocks 0..770: EQ = masked exp(Q) (+masked transpose). blocks 771..834:
// per-batch log_softmax + prefix-sum (fp64 master in scratch, fp32 in ws).
__global__ __launch_bounds__(256) void k_pre(const float* __restrict__ logits,
                                             const float* __restrict__ Q,
                                             const int* __restrict__ ls,
                                             float* __restrict__ ws,
                                             float* __restrict__ scr,
                                             float* __restrict__ out) {
  const int blk = blockIdx.x;
  const int tid = threadIdx.x;
  if (blk < 3 * S1) {
    const int c = blk / S1, i = blk - c * S1;
    float* EQ  = scr + SC_EQ;
    float* EQT = scr + SC_EQT;
    const float* Qr = Q + c * CH + i * S1;
    for (int j = tid; j < S1; j += 256) {
      float e = __expf(Qr[j]);
      EQ [c * EQC + i * EQP + j] = ((i < j) || (i == 256)) ? e : 0.f; // coalesced
      EQT[c * EQC + j * EQP + i] = ((j > i) || (j == 256)) ? e : 0.f; // scatter
    }
    return;
  }
  const int b = blk - 3 * S1;
  __shared__ float sC[3][256];
  {
    float l0 = logits[(b*3+0)*256 + tid];
    float l1 = logits[(b*3+1)*256 + tid];
    float l2 = logits[(b*3+2)*256 + tid];
    float mm = fmaxf(l0, fmaxf(l1, l2));
    float lse = mm + __logf(__expf(l0-mm) + __expf(l1-mm) + __expf(l2-mm));
    sC[0][tid] = l0 - lse;
    sC[1][tid] = l1 - lse;
    sC[2][tid] = l2 - lse;
  }
  __syncthreads();
  const int w = tid >> 6, lane = tid & 63;
  double* csD = (double*)(scr + SC_CSD);
  if (w < 3) {
    float*  cs32 = ws + WS_CS + b*771 + w*257;
    double* csd  = csD + b*771 + w*257;
    if (lane == 0) { cs32[0] = 0.f; csd[0] = 0.0; }
    double carry = 0.0;
    for (int t = 0; t < 4; ++t) {
      double v = (double)sC[w][t*64 + lane];
      #pragma unroll
      for (int off = 1; off < 64; off <<= 1) {
        double o = __shfl_up(v, off);
        if (lane >= off) v += o;
      }
      double r = carry + v;
      cs32[t*64 + lane + 1] = (float)r;
      csd [t*64 + lane + 1] = r;
      carry += __shfl(v, 63);
    }
  }
  if (tid == 0) out[OFF_LS + b] = (float)ls[b];
}

// ---------------------------------------------------------------- recursion
// Raw fp64 linear recursion (range fits fp64). blocks 0..63 alpha, 64..127
// beta. 1024 thr = 16 waves; wave w owns rows [16w,16w+16); lane owns 4 cols.
// EQ/EQT are PRE-MASKED (invalid entries = 0) -> no per-element selects;
// fully-invalid lanes skip their loads (triangular byte saving).
__global__ __launch_bounds__(1024) void k_rec(const float* __restrict__ scr,
                                              const int* __restrict__ pattern,
                                              const int* __restrict__ ls,
                                              float* __restrict__ ws,
                                              float* __restrict__ out) {
  __shared__ double ecsP[3][257], ecsM[3][257];
  __shared__ double wDp[2][258];    // weight vec (parity); [*][256] = raw A[256] (alpha) / wD256 (beta)
  __shared__ double AD[258];        // beta only: raw B state
  __shared__ double part[16][260];  // per-wave partials; [w][256] = col/row-256 partial
  __shared__ int patS[LEN];
  const int tid = threadIdx.x;
  const bool isBeta = (blockIdx.x >= BN);
  const int b = isBeta ? (blockIdx.x - BN) : blockIdx.x;
  const float* EQ  = scr + SC_EQ;
  const float* EQT = scr + SC_EQT;
  const double* csD = (const double*)(scr + SC_CSD) + b * 771;

  if (tid < LEN) patS[tid] = pattern[tid];
  const int lsb = ls[b];
  for (int idx = tid; idx < 771; idx += 1024) {
    int c = idx / 257, j = idx - c * 257;
    double x = csD[idx];
    ecsP[c][j] = dexp(x);
    ecsM[c][j] = dexp(-x);
  }
  float* outab = out + (isBeta ? OFF_B : OFF_A) + b * (ROWS * S1);
  const int w = tid >> 6, l = tid & 63;
  const int k0 = w << 4, col0 = l << 2;

  if (tid < S1) {
    if (!isBeta) {
      wDp[0][tid] = (tid == 0) ? 1.0 : 0.0;
      __builtin_nontemporal_store((tid == 0) ? 0.f : NEGV, &outab[tid]);
    } else {
      AD[tid] = (tid == lsb) ? 1.0 : 0.0;
      wDp[0][tid] = (tid == lsb) ? ecsP[patS[LEN-1]][tid] : 0.0;
      __builtin_nontemporal_store((tid == lsb) ? 0.f : NEGV, &outab[LEN * S1 + tid]);
    }
  }
  __syncthreads();

  int cur = 0;
  if (!isBeta) {
    for (int step = 0; step < LEN; ++step, cur ^= 1) {
      const int c = patS[step];
      const float* EQc  = EQ  + c * EQC;
      const float* EQTc = EQT + c * EQC;
      {  // matvec partials: cols col0..col0+3, rows k0..k0+15 (masked EQ)
        const double* wc = wDp[cur];
        double a0 = 0, a1 = 0, a2 = 0, a3 = 0;
        if (k0 < col0 + 3) {                    // any valid (k<col) element?
          const float* bp = EQc + k0 * EQP + col0;
          #pragma unroll
          for (int kk = 0; kk < 16; ++kk) {
            float4 e = *(const float4*)(bp + kk * EQP);
            double wv = wc[k0 + kk];
            a0 += wv * (double)e.x;
            a1 += wv * (double)e.y;
            a2 += wv * (double)e.z;
            a3 += wv * (double)e.w;
          }
        }
        part[w][col0] = a0; part[w][col0+1] = a1;
        part[w][col0+2] = a2; part[w][col0+3] = a3;
        double c2 = 0;                          // col-256 partial
        if (l < 16) c2 = wc[k0 + l] * (double)EQTc[256 * EQP + k0 + l];
        c2 += __shfl_xor(c2, 1); c2 += __shfl_xor(c2, 2);
        c2 += __shfl_xor(c2, 4); c2 += __shfl_xor(c2, 8);
        if (l == 0) part[w][256] = c2;
      }
      __syncthreads();
      if (tid < S1) {
        const int j = tid;
        double sum = 0;
        #pragma unroll
        for (int w2 = 0; w2 < 16; ++w2) sum += part[w2][j];
        double Ar = ecsP[c][j] * sum + wDp[cur][256] * (double)EQc[256 * EQP + j];
        float lo = dlogf(Ar);
        __builtin_nontemporal_store(lo, &outab[(step + 1) * S1 + j]);
        if (step == LEN - 1) {
          if (j == lsb) { out[OFF_M + b] = lo; ws[WS_M + b] = lo; }
        } else {
          const int cn = patS[step + 1];
          wDp[cur ^ 1][j] = (j < 256) ? Ar * ecsM[cn][j] : Ar;
        }
      }
      __syncthreads();
    }
  } else {
    for (int ss = 0; ss < LEN; ++ss, cur ^= 1) {
      const int step = LEN - 1 - ss;
      const int c = patS[step];
      const float* EQc  = EQ  + c * EQC;
      const float* EQTc = EQT + c * EQC;
      {  // partials for output rows i=col0.., k walks j in [k0,k0+16) (masked EQT)
        const double* wc = wDp[cur];
        double a0 = 0, a1 = 0, a2 = 0, a3 = 0;
        if (col0 < k0 + 15) {                   // any valid (k>col) element?
          const float* bp = EQTc + k0 * EQP + col0;
          #pragma unroll
          for (int kk = 0; kk < 16; ++kk) {
            float4 e = *(const float4*)(bp + kk * EQP);
            double wv = wc[k0 + kk];
            a0 += wv * (double)e.x;
            a1 += wv * (double)e.y;
            a2 += wv * (double)e.z;
            a3 += wv * (double)e.w;
          }
        }
        part[w][col0] = a0; part[w][col0+1] = a1;
        part[w][col0+2] = a2; part[w][col0+3] = a3;
        double r2 = 0;                          // row-256 output partial
        if (l < 16) r2 = AD[k0 + l] * (double)EQc[256 * EQP + k0 + l];
        r2 += __shfl_xor(r2, 1); r2 += __shfl_xor(r2, 2);
        r2 += __shfl_xor(r2, 4); r2 += __shfl_xor(r2, 8);
        if (l == 0) part[w][256] = r2;
      }
      __syncthreads();
      if (tid < S1) {
        const int i = tid;
        double sum = 0;
        #pragma unroll
        for (int w2 = 0; w2 < 16; ++w2) sum += part[w2][i];
        double Ar;
        if (i < 256)
          Ar = ecsM[c][i] * (sum + (double)EQTc[256 * EQP + i] * wDp[cur][256]);
        else
          Ar = sum + (double)EQc[256 * EQP + 256] * AD[256];
        __builtin_nontemporal_store(dlogf(Ar), &outab[step * S1 + i]);
        AD[i] = Ar;
        if (ss < LEN - 1) {
          const int cn = patS[step - 1];
          wDp[cur ^ 1][i] = Ar * ecsP[cn][i];
        }
      }
      __syncthreads();
    }
  }
}

// ---------------------------------------------------------------- ll & p
__global__ __launch_bounds__(256) void k_llp(const float* __restrict__ ws,
                                             float* __restrict__ out) {
  int idx = blockIdx.x * 256 + threadIdx.x;
  if (idx >= ABSZ) return;
  int b = idx / (ROWS * S1);
  float a = out[OFF_A + idx];
  float bb = out[OFF_B + idx];
  float ll = a + bb;
  __builtin_nontemporal_store(ll, out + OFF_LL + idx);
  __builtin_nontemporal_store(ll - ws[WS_M + b], out + OFF_P + idx);
}

// ---------------------------------------------------------------- t (541 MB)
__global__ __launch_bounds__(256) void k_t(const float* __restrict__ Q,
                                           const int* __restrict__ pattern,
                                           const float* __restrict__ ws,
                                           float* __restrict__ out) {
  __shared__ float r1[257], r2[257], c1[257], c2[257];
  const int bk = blockIdx.x;
  const int b = bk >> 5, k = bk & 31;
  const int c = pattern[k];
  const float Mb = ws[WS_M + b];
  const int tid = threadIdx.x;
  const float* cs = ws + WS_CS + b*771 + c*257;
  const float* ar = out + OFF_A + (b*ROWS + k) * S1;
  const float* br = out + OFF_B + (b*ROWS + k + 1) * S1;
  for (int i = tid; i < S1; i += 256) {
    float av = ar[i], cv = cs[i], bv = br[i];
    r1[i] = av - cv - Mb;                        // j > i : P = cs[j]-cs[i]
    r2[i] = av - Mb + ((i == 256) ? 0.f : NEGV); // row 256: P=0, else NEG
    c1[i] = bv + cv;
    c2[i] = bv;
  }
  __syncthreads();
  const float* Qc = Q + c*CH;
  float* tb = out + OFF_T + (size_t)bk * CH;
  int i = 0, j = tid;                            // idx = i*257 + j diagonal march
  for (int idx = tid; idx < CH; idx += 256) {
    float qv = Qc[idx];
    float v = (j > i) ? (r1[i] + c1[j]) : (r2[i] + c2[j]);
    __builtin_nontemporal_store(qv + v, tb + idx);
    bool wr = (j == 0);
    i += wr ? 0 : 1;
    j = wr ? 256 : (j - 1);
  }
}

extern "C" void kernel_launch(void* const* d_in, const int* in_sizes, int n_in,
                              void* d_out, int out_size, void* d_ws, size_t ws_size,
                              hipStream_t stream) {
  const float* logits = (const float*)d_in[0];
  const float* Q      = (const float*)d_in[1];
  const int* pattern  = (const int*)d_in[2];
  const int* ls       = (const int*)d_in[3];
  float* out = (float*)d_out;
  float* ws  = (float*)d_ws;

  // scratch in ws (L2-friendly, proven cached in round 1) if it fits,
  // else fall back to the not-yet-written t-region of d_out.
  const size_t need = (size_t)(WS_SCR + SC_END) * sizeof(float);
  float* scr = (ws_size >= need) ? (ws + WS_SCR) : (out + OFF_T);

  k_pre<<<3*S1 + BN, 256, 0, stream>>>(logits, Q, ls, ws, scr, out);
  k_rec<<<2*BN, 1024, 0, stream>>>(scr, pattern, ls, ws, out);
  k_llp<<<(ABSZ + 255)/256, 256, 0, stream>>>(ws, out);
  k_t<<<BN*LEN, 256, 0, stream>>>(Q, pattern, ws, out);
}